// Round 2
// baseline (929.016 us; speedup 1.0000x reference)
//
#include <hip/hip_runtime.h>

typedef unsigned short u16;
typedef __attribute__((ext_vector_type(8))) short short8;
typedef __attribute__((ext_vector_type(8))) unsigned short ushort8;
typedef __attribute__((ext_vector_type(4))) unsigned short ushort4v;
typedef __attribute__((ext_vector_type(4))) float f32x4;

#define NB 4
#define SS 4096
#define DD 1024

__device__ __forceinline__ u16 f2bf(float x) {
  unsigned u = __builtin_bit_cast(unsigned, x);
  u = (u + 0x7FFFu + ((u >> 16) & 1u)) >> 16;
  return (u16)u;
}
__device__ __forceinline__ float bf2f(u16 b) {
  unsigned u = ((unsigned)b) << 16;
  return __builtin_bit_cast(float, u);
}
__device__ __forceinline__ void gload16(const void* g, void* l) {
  __builtin_amdgcn_global_load_lds((const __attribute__((address_space(1))) void*)g,
                                   (__attribute__((address_space(3))) void*)l, 16, 0, 0);
}
// bijective XCD-aware swizzle (m204): consecutive swz ids land on one XCD
__device__ __forceinline__ int xcd_swz(int bid, int nwg) {
  const int x = bid & 7, idx = bid >> 3;
  const int q = nwg >> 3, r = nwg & 7;
  return (x < r ? x * (q + 1) : r * (q + 1) + (x - r) * q) + idx;
}

// ---------------- kernel 1: logits (f32), loss partials, pred, h->bf16 -----
__global__ __launch_bounds__(256) void k_logits(
    const float* __restrict__ h, const int* __restrict__ lab,
    const float* __restrict__ Wl, const float* __restrict__ bl,
    u16* __restrict__ h16, int* __restrict__ pred, float* __restrict__ lossPart)
{
  const int t = threadIdx.x, w = t >> 6, lane = t & 63;
  const int tok = blockIdx.x * 4 + w;
  const float4* h4p = (const float4*)(h + (size_t)tok * DD);
  const float4* wl4 = (const float4*)Wl;  // Wl row d = one float4
  float p0 = 0.f, p1 = 0.f, p2 = 0.f, p3 = 0.f;
#pragma unroll
  for (int i = 0; i < 4; ++i) {
    const int d = i * 256 + lane * 4;
    float4 hv = h4p[i * 64 + lane];
    ushort4v hb;
    hb[0] = f2bf(hv.x); hb[1] = f2bf(hv.y); hb[2] = f2bf(hv.z); hb[3] = f2bf(hv.w);
    *(ushort4v*)(h16 + (size_t)tok * DD + d) = hb;
    float4 w0 = wl4[d], w1 = wl4[d + 1], w2 = wl4[d + 2], w3 = wl4[d + 3];
    p0 += hv.x * w0.x + hv.y * w1.x + hv.z * w2.x + hv.w * w3.x;
    p1 += hv.x * w0.y + hv.y * w1.y + hv.z * w2.y + hv.w * w3.y;
    p2 += hv.x * w0.z + hv.y * w1.z + hv.z * w2.z + hv.w * w3.z;
    p3 += hv.x * w0.w + hv.y * w1.w + hv.z * w2.w + hv.w * w3.w;
  }
#pragma unroll
  for (int m = 32; m; m >>= 1) {
    p0 += __shfl_xor(p0, m); p1 += __shfl_xor(p1, m);
    p2 += __shfl_xor(p2, m); p3 += __shfl_xor(p3, m);
  }
  __shared__ float ls[4];
  if (lane == 0) {
    float l[4] = {p0 + bl[0], p1 + bl[1], p2 + bl[2], p3 + bl[3]};
    int bi = 0; float bv = l[0];
#pragma unroll
    for (int c = 1; c < 4; ++c) if (l[c] > bv) { bv = l[c]; bi = c; }  // first-max like np.argmax
    pred[tok] = bi;
    float se = 0.f;
#pragma unroll
    for (int c = 0; c < 4; ++c) se += expf(l[c] - bv);
    float lse = bv + logf(se);
    ls[w] = lse - l[lab[tok]];
  }
  __syncthreads();
  if (t == 0) lossPart[blockIdx.x] = ls[0] + ls[1] + ls[2] + ls[3];
}

// ---------------- kernel 2: weights -> transposed bf16 ---------------------
__global__ __launch_bounds__(256) void k_wconv(
    const float* __restrict__ W0, const float* __restrict__ W1,
    const float* __restrict__ W2, const float* __restrict__ W3,
    u16* __restrict__ Wt)
{
  const int gid = blockIdx.x * 256 + threadIdx.x;
  const int mat = gid >> 20;
  const int rem = gid & ((1 << 20) - 1);
  const int n = rem >> 10, k = rem & 1023;
  const float* W = (mat == 0) ? W0 : (mat == 1) ? W1 : (mat == 2) ? W2 : W3;
  Wt[((size_t)mat << 20) + (size_t)n * 1024 + k] = f2bf(W[(size_t)k * 1024 + n]);
}

// ---------------- kernel 3: BIOS chunk scan (1 block / batch) --------------
__global__ __launch_bounds__(256) void k_scan(
    const int* __restrict__ pred, int* __restrict__ cstart, int* __restrict__ ccnt)
{
  const int b = blockIdx.x, t = threadIdx.x;
  const int4* p4 = (const int4*)(pred + (size_t)b * SS);
  int labv[16];
#pragma unroll
  for (int i = 0; i < 4; ++i) {
    int4 v = p4[t * 4 + i];
    labv[i * 4 + 0] = v.x; labv[i * 4 + 1] = v.y;
    labv[i * 4 + 2] = v.z; labv[i * 4 + 3] = v.w;
  }
  // transfer fn ext' = a | (b & ext): compose over the thread's 16 tokens
  int A = 0, Bc = 1;
#pragma unroll
  for (int e = 0; e < 16; ++e) {
    int a = (labv[e] == 0), bb = (labv[e] == 1);
    A = a | (bb & A);
    Bc = bb & Bc;
  }
  __shared__ int sA[256], sB[256], sC[256];
  sA[t] = A; sB[t] = Bc;
  __syncthreads();
  for (int off = 1; off < 256; off <<= 1) {  // inclusive Hillis-Steele
    int pa = 0, pb = 1;
    if (t >= off) { pa = sA[t - off]; pb = sB[t - off]; }
    __syncthreads();
    A = A | (Bc & pa); Bc = Bc & pb;
    sA[t] = A; sB[t] = Bc;
    __syncthreads();
  }
  const int extIn = (t == 0) ? 0 : sA[t - 1];
  int ext = extIn, nst = 0;
#pragma unroll
  for (int e = 0; e < 16; ++e) {
    int cont = (labv[e] == 1) & ext;
    nst += !cont;
    ext = (labv[e] == 0) | cont;
  }
  sC[t] = nst;
  __syncthreads();
  int tot = nst;
  for (int off = 1; off < 256; off <<= 1) {
    int pc = 0;
    if (t >= off) pc = sC[t - off];
    __syncthreads();
    tot += pc;
    sC[t] = tot;
    __syncthreads();
  }
  const int base = tot - nst;
  const int total = sC[255];
  if (t == 0) { ccnt[b] = total; cstart[b * (SS + 1) + total] = SS; }  // sentinel
  ext = extIn; int id = base;
#pragma unroll
  for (int e = 0; e < 16; ++e) {
    int cont = (labv[e] == 1) & ext;
    if (!cont) cstart[b * (SS + 1) + id++] = t * 16 + e;
    ext = (labv[e] == 0) | cont;
  }
}

// ---------------- kernel 4: segment-mean pooling (1 wave / chunk) ----------
__global__ __launch_bounds__(256) void k_pool(
    const float* __restrict__ h, const int* __restrict__ cstart,
    const int* __restrict__ ccnt, u16* __restrict__ cemb)
{
  const int t = threadIdx.x, w = t >> 6, lane = t & 63;
  const int gw = blockIdx.x * 4 + w;
  const int b = gw >> 12, c = gw & (SS - 1);
  u16* out = cemb + (size_t)gw * DD + lane * 16;
  if (c >= ccnt[b]) {
    ushort8 z = {0, 0, 0, 0, 0, 0, 0, 0};
    *(ushort8*)out = z; *(ushort8*)(out + 8) = z;
    return;
  }
  const int s0 = cstart[b * (SS + 1) + c], s1 = cstart[b * (SS + 1) + c + 1];
  float acc[16] = {};
  for (int s = s0; s < s1; ++s) {
    const float4* hp = (const float4*)(h + ((size_t)b * SS + s) * DD + lane * 16);
#pragma unroll
    for (int ii = 0; ii < 4; ++ii) {
      float4 v = hp[ii];
      acc[ii * 4 + 0] += v.x; acc[ii * 4 + 1] += v.y;
      acc[ii * 4 + 2] += v.z; acc[ii * 4 + 3] += v.w;
    }
  }
  const float inv = 1.f / (float)(s1 - s0);
  ushort8 o0, o1;
#pragma unroll
  for (int e = 0; e < 8; ++e) { o0[e] = f2bf(acc[e] * inv); o1[e] = f2bf(acc[8 + e] * inv); }
  *(ushort8*)out = o0; *(ushort8*)(out + 8) = o1;
}

// ---------------- NT bf16 GEMM: C[m,n] = scale*sum_k A[m,k]*Bt[n,k] + bias[n]
// 128x128 tile, BK=64, 4 waves, global_load_lds w=16, 16x16x32 MFMA (m97 structure)
// builtin MFMA (compiler schedules lgkmcnt interleave) + bijective XCD swizzle
template <int OUTF32>
__global__ __launch_bounds__(256) void gemm_nt(
    const u16* __restrict__ A, const u16* __restrict__ Bt, void* __restrict__ Cp,
    const float* __restrict__ bias, float scale, int M, int N, int K)
{
  __shared__ u16 lsA[128 * 64], lsB[128 * 64];
  const int t = threadIdx.x, lane = t & 63, w = t >> 6;
  const int wr = w >> 1, wc = w & 1;
  const int bid = blockIdx.y * gridDim.x + blockIdx.x;
  const int swz = xcd_swz(bid, gridDim.x * gridDim.y);
  const int m0 = (swz / gridDim.x) * 128, n0 = (swz % gridDim.x) * 128;
  const f32x4 zero = {0.f, 0.f, 0.f, 0.f};
  f32x4 acc[4][4];
#pragma unroll
  for (int i = 0; i < 4; ++i)
#pragma unroll
    for (int j = 0; j < 4; ++j) acc[i][j] = zero;

  const u16* Ag = A + (size_t)(m0 + (t >> 3)) * K + (t & 7) * 8;
  const u16* Bg = Bt + (size_t)(n0 + (t >> 3)) * K + (t & 7) * 8;
  u16* lA = lsA + t * 8;  // byte off t*16 = wave-uniform base + lane*16
  u16* lB = lsB + t * 8;

  for (int kt = 0; kt < K; kt += 64) {
#pragma unroll
    for (int p = 0; p < 4; ++p) {
      gload16(Ag + (size_t)(p * 32) * K + kt, lA + p * 2048);
      gload16(Bg + (size_t)(p * 32) * K + kt, lB + p * 2048);
    }
    __syncthreads();  // compiler emits vmcnt(0) drain before barrier
#pragma unroll
    for (int kk = 0; kk < 2; ++kk) {
      short8 af[4], bfv[4];
      const int lrow = lane & 15, lk = kk * 32 + (lane >> 4) * 8;
#pragma unroll
      for (int i = 0; i < 4; ++i)
        af[i] = *(const short8*)(lsA + (wr * 64 + i * 16 + lrow) * 64 + lk);
#pragma unroll
      for (int j = 0; j < 4; ++j)
        bfv[j] = *(const short8*)(lsB + (wc * 64 + j * 16 + lrow) * 64 + lk);
#pragma unroll
      for (int i = 0; i < 4; ++i)
#pragma unroll
        for (int j = 0; j < 4; ++j)
          acc[i][j] = __builtin_amdgcn_mfma_f32_16x16x32_bf16(af[i], bfv[j], acc[i][j], 0, 0, 0);
    }
    __syncthreads();
  }
  // epilogue: C/D layout col=lane&15, row=(lane>>4)*4+q
  const int colb = n0 + wc * 64 + (lane & 15);
  const int rowb = m0 + wr * 64 + (lane >> 4) * 4;
#pragma unroll
  for (int j = 0; j < 4; ++j) {
    const int col = colb + j * 16;
    const float bv = bias ? bias[col] : 0.f;
#pragma unroll
    for (int i = 0; i < 4; ++i) {
#pragma unroll
      for (int q = 0; q < 4; ++q) {
        const float v = acc[i][j][q] * scale + bv;
        const size_t idx = (size_t)(rowb + i * 16 + q) * N + col;
        if (OUTF32) ((float*)Cp)[idx] = v;
        else        ((u16*)Cp)[idx]  = f2bf(v);
      }
    }
  }
}

// ---------------- masked row softmax, bf16 in-place -------------------------
__global__ __launch_bounds__(256) void k_softmax(
    u16* __restrict__ sc, const int* __restrict__ ccnt, int b)
{
  const int t = threadIdx.x, lane = t & 63, w = t >> 6;
  const int row = blockIdx.x;
  const int Cb = ccnt[b];
  u16* p = sc + (size_t)row * SS + t * 16;
  ushort8 v0 = *(ushort8*)p, v1 = *(ushort8*)(p + 8);
  float x[16];
#pragma unroll
  for (int e = 0; e < 8; ++e) { x[e] = bf2f(v0[e]); x[8 + e] = bf2f(v1[e]); }
  const int cb0 = t * 16;
  float m = -1e30f;
#pragma unroll
  for (int e = 0; e < 16; ++e) if (cb0 + e < Cb) m = fmaxf(m, x[e]);
#pragma unroll
  for (int off = 32; off; off >>= 1) m = fmaxf(m, __shfl_xor(m, off));
  __shared__ float red[4], red2[4];
  if (lane == 0) red[w] = m;
  __syncthreads();
  m = fmaxf(fmaxf(red[0], red[1]), fmaxf(red[2], red[3]));
  float ssum = 0.f;
#pragma unroll
  for (int e = 0; e < 16; ++e) {
    float ev = (cb0 + e < Cb) ? __expf(x[e] - m) : 0.f;
    x[e] = ev; ssum += ev;
  }
#pragma unroll
  for (int off = 32; off; off >>= 1) ssum += __shfl_xor(ssum, off);
  if (lane == 0) red2[w] = ssum;
  __syncthreads();
  ssum = red2[0] + red2[1] + red2[2] + red2[3];
  const float inv = 1.f / ssum;
#pragma unroll
  for (int e = 0; e < 8; ++e) { v0[e] = f2bf(x[e] * inv); v1[e] = f2bf(x[8 + e] * inv); }
  *(ushort8*)p = v0; *(ushort8*)(p + 8) = v1;
}

// ---------------- bf16 transpose v[b][c][d] -> vT[b][d][c] ------------------
__global__ __launch_bounds__(256) void k_transpose(
    const u16* __restrict__ v, u16* __restrict__ vt)
{
  __shared__ u16 ts[64][80];  // row stride 160B keeps 16B alignment
  const int t = threadIdx.x;
  const int d0 = blockIdx.x * 64, c0 = blockIdx.y * 64, b = blockIdx.z;
#pragma unroll
  for (int p = 0; p < 2; ++p) {
    const int idx = p * 256 + t, r = idx >> 3, cc = idx & 7;
    ushort8 val = *(const ushort8*)(v + ((size_t)b * SS + c0 + r) * DD + d0 + cc * 8);
    *(ushort8*)&ts[r][cc * 8] = val;
  }
  __syncthreads();
#pragma unroll
  for (int p = 0; p < 2; ++p) {
    const int idx = p * 256 + t, r = idx >> 3, cc = idx & 7;
    ushort8 o;
#pragma unroll
    for (int e = 0; e < 8; ++e) o[e] = ts[cc * 8 + e][r];
    *(ushort8*)(vt + ((size_t)b * DD + d0 + r) * SS + c0 + cc * 8) = o;
  }
}

// ---------------- loss finalize ---------------------------------------------
__global__ __launch_bounds__(256) void k_lossfin(
    const float* __restrict__ part, float* __restrict__ out)
{
  const int t = threadIdx.x, lane = t & 63, w = t >> 6;
  float s = 0.f;
  for (int i = t; i < 4096; i += 256) s += part[i];
#pragma unroll
  for (int off = 32; off; off >>= 1) s += __shfl_xor(s, off);
  __shared__ float r[4];
  if (lane == 0) r[w] = s;
  __syncthreads();
  if (t == 0) out[0] = (r[0] + r[1] + r[2] + r[3]) * (1.f / (NB * SS));
}

extern "C" void kernel_launch(void* const* d_in, const int* in_sizes, int n_in,
                              void* d_out, int out_size, void* d_ws, size_t ws_size,
                              hipStream_t stream) {
  const float* h  = (const float*)d_in[0];
  const int* plab = (const int*)d_in[1];
  const float* Wl = (const float*)d_in[2];
  const float* bl = (const float*)d_in[3];
  const float* Wq = (const float*)d_in[4];
  const float* bq = (const float*)d_in[5];
  const float* Wk = (const float*)d_in[6];
  const float* bk = (const float*)d_in[7];
  const float* Wv = (const float*)d_in[8];
  const float* bv = (const float*)d_in[9];
  const float* Wo = (const float*)d_in[10];
  const float* bo = (const float*)d_in[11];
  float* out = (float*)d_out;

  char* ws = (char*)d_ws;
  const size_t SZ = (size_t)NB * SS * DD * 2;  // 32 MB (bf16 [B*S, D])
  u16* h16      = (u16*)(ws + 0 * SZ);  // dead after q GEMM -> aliases scores
  u16* cemb     = (u16*)(ws + 1 * SZ);  // dead after k,v GEMM -> aliases attended
  u16* q        = (u16*)(ws + 2 * SZ);
  u16* kk       = (u16*)(ws + 3 * SZ);
  u16* vv       = (u16*)(ws + 4 * SZ);
  u16* vt       = (u16*)(ws + 5 * SZ);
  u16* Wt       = (u16*)(ws + 6 * SZ);                     // 4 x 1024x1024 bf16 = 8 MB
  char* ws2     = ws + 6 * SZ + (size_t)4 * 1024 * 1024 * 2;
  int* pred     = (int*)ws2;                               // 64 KB
  int* cstart   = (int*)(ws2 + 65536);                     // 4*(S+1) ints
  int* ccnt     = (int*)(ws2 + 65536 + 4 * (SS + 1) * 4);
  float* lossPart = (float*)(ws2 + 65536 + 4 * (SS + 1) * 4 + 64);
  u16* scores   = h16;   // per-batch [S,S] bf16 = 32 MB, alias (q GEMM completes first)
  u16* attended = cemb;  // [B*S, D] bf16, alias (k,v GEMMs complete first)

  k_logits<<<dim3(NB * SS / 4), 256, 0, stream>>>(h, plab, Wl, bl, h16, pred, lossPart);
  k_wconv<<<dim3(4 * 1024 * 1024 / 256), 256, 0, stream>>>(Wq, Wk, Wv, Wo, Wt);
  k_scan<<<dim3(NB), 256, 0, stream>>>(pred, cstart, ccnt);
  k_pool<<<dim3(NB * SS / 4), 256, 0, stream>>>(h, cstart, ccnt, cemb);

  gemm_nt<0><<<dim3(DD / 128, NB * SS / 128), 256, 0, stream>>>(
      h16, Wt, q, bq, 1.f, NB * SS, DD, DD);
  gemm_nt<0><<<dim3(DD / 128, NB * SS / 128), 256, 0, stream>>>(
      cemb, Wt + (1 << 20), kk, bk, 1.f, NB * SS, DD, DD);
  gemm_nt<0><<<dim3(DD / 128, NB * SS / 128), 256, 0, stream>>>(
      cemb, Wt + 2 * (1 << 20), vv, bv, 1.f, NB * SS, DD, DD);
  k_transpose<<<dim3(DD / 64, SS / 64, NB), 256, 0, stream>>>(vv, vt);

  const float scl = 1.f / 32.f;  // 1/sqrt(DC)
  for (int b = 0; b < NB; ++b) {
    gemm_nt<0><<<dim3(SS / 128, SS / 128), 256, 0, stream>>>(
        q + (size_t)b * SS * DD, kk + (size_t)b * SS * DD, scores, nullptr, scl, SS, SS, DD);
    k_softmax<<<dim3(SS), 256, 0, stream>>>(scores, ccnt, b);
    gemm_nt<0><<<dim3(DD / 128, SS / 128), 256, 0, stream>>>(
        scores, vt + (size_t)b * DD * SS, attended + (size_t)b * SS * DD, nullptr, 1.f, SS, DD, SS);
  }
  gemm_nt<1><<<dim3(DD / 128, NB * SS / 128), 256, 0, stream>>>(
      attended, Wt + 3 * (1 << 20), out, bo, 1.f, NB * SS, DD, DD);
  k_lossfin<<<dim3(1), 256, 0, stream>>>(lossPart, out + (size_t)NB * SS * DD);
}

// Round 3
// 816.596 us; speedup vs baseline: 1.1377x; 1.1377x over previous
//
#include <hip/hip_runtime.h>

typedef unsigned short u16;
typedef __attribute__((ext_vector_type(8))) short short8;
typedef __attribute__((ext_vector_type(8))) unsigned short ushort8;
typedef __attribute__((ext_vector_type(4))) unsigned short ushort4v;
typedef __attribute__((ext_vector_type(4))) float f32x4;

#define NB 4
#define SS 4096
#define DD 1024

__device__ __forceinline__ u16 f2bf(float x) {
  unsigned u = __builtin_bit_cast(unsigned, x);
  u = (u + 0x7FFFu + ((u >> 16) & 1u)) >> 16;
  return (u16)u;
}
__device__ __forceinline__ float bf2f(u16 b) {
  unsigned u = ((unsigned)b) << 16;
  return __builtin_bit_cast(float, u);
}
__device__ __forceinline__ void gload16(const void* g, void* l) {
  __builtin_amdgcn_global_load_lds((const __attribute__((address_space(1))) void*)g,
                                   (__attribute__((address_space(3))) void*)l, 16, 0, 0);
}
// bijective XCD-aware swizzle (m204): consecutive swz ids land on one XCD
__device__ __forceinline__ int xcd_swz(int bid, int nwg) {
  const int x = bid & 7, idx = bid >> 3;
  const int q = nwg >> 3, r = nwg & 7;
  return (x < r ? x * (q + 1) : r * (q + 1) + (x - r) * q) + idx;
}

// ---------------- kernel 1: logits (f32), loss partials, pred, h->bf16 -----
__global__ __launch_bounds__(256) void k_logits(
    const float* __restrict__ h, const int* __restrict__ lab,
    const float* __restrict__ Wl, const float* __restrict__ bl,
    u16* __restrict__ h16, int* __restrict__ pred, float* __restrict__ lossPart)
{
  const int t = threadIdx.x, w = t >> 6, lane = t & 63;
  const int tok = blockIdx.x * 4 + w;
  const float4* h4p = (const float4*)(h + (size_t)tok * DD);
  const float4* wl4 = (const float4*)Wl;  // Wl row d = one float4
  float p0 = 0.f, p1 = 0.f, p2 = 0.f, p3 = 0.f;
#pragma unroll
  for (int i = 0; i < 4; ++i) {
    const int d = i * 256 + lane * 4;
    float4 hv = h4p[i * 64 + lane];
    ushort4v hb;
    hb[0] = f2bf(hv.x); hb[1] = f2bf(hv.y); hb[2] = f2bf(hv.z); hb[3] = f2bf(hv.w);
    *(ushort4v*)(h16 + (size_t)tok * DD + d) = hb;
    float4 w0 = wl4[d], w1 = wl4[d + 1], w2 = wl4[d + 2], w3 = wl4[d + 3];
    p0 += hv.x * w0.x + hv.y * w1.x + hv.z * w2.x + hv.w * w3.x;
    p1 += hv.x * w0.y + hv.y * w1.y + hv.z * w2.y + hv.w * w3.y;
    p2 += hv.x * w0.z + hv.y * w1.z + hv.z * w2.z + hv.w * w3.z;
    p3 += hv.x * w0.w + hv.y * w1.w + hv.z * w2.w + hv.w * w3.w;
  }
#pragma unroll
  for (int m = 32; m; m >>= 1) {
    p0 += __shfl_xor(p0, m); p1 += __shfl_xor(p1, m);
    p2 += __shfl_xor(p2, m); p3 += __shfl_xor(p3, m);
  }
  __shared__ float ls[4];
  if (lane == 0) {
    float l[4] = {p0 + bl[0], p1 + bl[1], p2 + bl[2], p3 + bl[3]};
    int bi = 0; float bv = l[0];
#pragma unroll
    for (int c = 1; c < 4; ++c) if (l[c] > bv) { bv = l[c]; bi = c; }  // first-max like np.argmax
    pred[tok] = bi;
    float se = 0.f;
#pragma unroll
    for (int c = 0; c < 4; ++c) se += expf(l[c] - bv);
    float lse = bv + logf(se);
    ls[w] = lse - l[lab[tok]];
  }
  __syncthreads();
  if (t == 0) lossPart[blockIdx.x] = ls[0] + ls[1] + ls[2] + ls[3];
}

// ---------------- kernel 2: weights -> transposed bf16 ---------------------
__global__ __launch_bounds__(256) void k_wconv(
    const float* __restrict__ W0, const float* __restrict__ W1,
    const float* __restrict__ W2, const float* __restrict__ W3,
    u16* __restrict__ Wt)
{
  const int gid = blockIdx.x * 256 + threadIdx.x;
  const int mat = gid >> 20;
  const int rem = gid & ((1 << 20) - 1);
  const int n = rem >> 10, k = rem & 1023;
  const float* W = (mat == 0) ? W0 : (mat == 1) ? W1 : (mat == 2) ? W2 : W3;
  Wt[((size_t)mat << 20) + (size_t)n * 1024 + k] = f2bf(W[(size_t)k * 1024 + n]);
}

// ---------------- kernel 3: BIOS chunk scan (1 block / batch) --------------
__global__ __launch_bounds__(256) void k_scan(
    const int* __restrict__ pred, int* __restrict__ cstart, int* __restrict__ ccnt)
{
  const int b = blockIdx.x, t = threadIdx.x;
  const int4* p4 = (const int4*)(pred + (size_t)b * SS);
  int labv[16];
#pragma unroll
  for (int i = 0; i < 4; ++i) {
    int4 v = p4[t * 4 + i];
    labv[i * 4 + 0] = v.x; labv[i * 4 + 1] = v.y;
    labv[i * 4 + 2] = v.z; labv[i * 4 + 3] = v.w;
  }
  // transfer fn ext' = a | (b & ext): compose over the thread's 16 tokens
  int A = 0, Bc = 1;
#pragma unroll
  for (int e = 0; e < 16; ++e) {
    int a = (labv[e] == 0), bb = (labv[e] == 1);
    A = a | (bb & A);
    Bc = bb & Bc;
  }
  __shared__ int sA[256], sB[256], sC[256];
  sA[t] = A; sB[t] = Bc;
  __syncthreads();
  for (int off = 1; off < 256; off <<= 1) {  // inclusive Hillis-Steele
    int pa = 0, pb = 1;
    if (t >= off) { pa = sA[t - off]; pb = sB[t - off]; }
    __syncthreads();
    A = A | (Bc & pa); Bc = Bc & pb;
    sA[t] = A; sB[t] = Bc;
    __syncthreads();
  }
  const int extIn = (t == 0) ? 0 : sA[t - 1];
  int ext = extIn, nst = 0;
#pragma unroll
  for (int e = 0; e < 16; ++e) {
    int cont = (labv[e] == 1) & ext;
    nst += !cont;
    ext = (labv[e] == 0) | cont;
  }
  sC[t] = nst;
  __syncthreads();
  int tot = nst;
  for (int off = 1; off < 256; off <<= 1) {
    int pc = 0;
    if (t >= off) pc = sC[t - off];
    __syncthreads();
    tot += pc;
    sC[t] = tot;
    __syncthreads();
  }
  const int base = tot - nst;
  const int total = sC[255];
  if (t == 0) { ccnt[b] = total; cstart[b * (SS + 1) + total] = SS; }  // sentinel
  ext = extIn; int id = base;
#pragma unroll
  for (int e = 0; e < 16; ++e) {
    int cont = (labv[e] == 1) & ext;
    if (!cont) cstart[b * (SS + 1) + id++] = t * 16 + e;
    ext = (labv[e] == 0) | cont;
  }
}

// ---------------- kernel 4: segment-mean pooling (1 wave / chunk) ----------
__global__ __launch_bounds__(256) void k_pool(
    const float* __restrict__ h, const int* __restrict__ cstart,
    const int* __restrict__ ccnt, u16* __restrict__ cemb)
{
  const int t = threadIdx.x, w = t >> 6, lane = t & 63;
  const int gw = blockIdx.x * 4 + w;
  const int b = gw >> 12, c = gw & (SS - 1);
  u16* out = cemb + (size_t)gw * DD + lane * 16;
  if (c >= ccnt[b]) {
    ushort8 z = {0, 0, 0, 0, 0, 0, 0, 0};
    *(ushort8*)out = z; *(ushort8*)(out + 8) = z;
    return;
  }
  const int s0 = cstart[b * (SS + 1) + c], s1 = cstart[b * (SS + 1) + c + 1];
  float acc[16] = {};
  for (int s = s0; s < s1; ++s) {
    const float4* hp = (const float4*)(h + ((size_t)b * SS + s) * DD + lane * 16);
#pragma unroll
    for (int ii = 0; ii < 4; ++ii) {
      float4 v = hp[ii];
      acc[ii * 4 + 0] += v.x; acc[ii * 4 + 1] += v.y;
      acc[ii * 4 + 2] += v.z; acc[ii * 4 + 3] += v.w;
    }
  }
  const float inv = 1.f / (float)(s1 - s0);
  ushort8 o0, o1;
#pragma unroll
  for (int e = 0; e < 8; ++e) { o0[e] = f2bf(acc[e] * inv); o1[e] = f2bf(acc[8 + e] * inv); }
  *(ushort8*)out = o0; *(ushort8*)(out + 8) = o1;
}

// ---------------- NT bf16 GEMM: C[m,n] = scale*sum_k A[m,k]*Bt[n,k] + bias[n]
// 128x128 tile, BK=64, 4 waves, 16x16x32 MFMA.
// This round: (a) bank-conflict fix via inverse-swizzled GLOBAL source +
// swizzled ds_read offset (rule 21: linear gload_lds dest, XOR involution);
// (b) minimum 2-phase double-buffer (stage t+1 before compute t, one barrier).
template <int OUTF32>
__global__ __launch_bounds__(256) void gemm_nt(
    const u16* __restrict__ A, const u16* __restrict__ Bt, void* __restrict__ Cp,
    const float* __restrict__ bias, float scale, int M, int N, int K)
{
  __shared__ u16 lsA[2 * 128 * 64], lsB[2 * 128 * 64];  // 64 KB total
  const int t = threadIdx.x, lane = t & 63, w = t >> 6;
  const int wr = w >> 1, wc = w & 1;
  const int bid = blockIdx.y * gridDim.x + blockIdx.x;
  const int swz = xcd_swz(bid, gridDim.x * gridDim.y);
  const int m0 = (swz / gridDim.x) * 128, n0 = (swz % gridDim.x) * 128;
  f32x4 acc[4][4];
#pragma unroll
  for (int i = 0; i < 4; ++i)
#pragma unroll
    for (int j = 0; j < 4; ++j) acc[i][j] = (f32x4){0.f, 0.f, 0.f, 0.f};

  // stage: source column chunk XOR'd with dest row&7 (involution). Dest row&7
  // = (t>>3)&7 because m0, w*8, p*32 are all ==0 mod 8.
  const int schunk = (t & 7) ^ ((t >> 3) & 7);
  const u16* Ag = A + (size_t)(m0 + (t >> 3)) * K + schunk * 8;
  const u16* Bg = Bt + (size_t)(n0 + (t >> 3)) * K + schunk * 8;
  u16* lA = lsA + t * 8;  // linear dest: wave-uniform base + lane*16B
  u16* lB = lsB + t * 8;

  const int lrow = lane & 15, hi = lane >> 4, sx = lrow & 7;
  // read offsets (u16 units) within a 64-elem row, chunk XOR-swizzled:
  const int lk0 = ((0 * 4 + hi) ^ sx) * 8;  // kk=0
  const int lk1 = ((1 * 4 + hi) ^ sx) * 8;  // kk=1

  auto compute = [&](const u16* bA, const u16* bB) {
#pragma unroll
    for (int kk = 0; kk < 2; ++kk) {
      const int lk = kk ? lk1 : lk0;
      short8 af[4], bfv[4];
#pragma unroll
      for (int i = 0; i < 4; ++i)
        af[i] = *(const short8*)(bA + (wr * 64 + i * 16 + lrow) * 64 + lk);
#pragma unroll
      for (int j = 0; j < 4; ++j)
        bfv[j] = *(const short8*)(bB + (wc * 64 + j * 16 + lrow) * 64 + lk);
#pragma unroll
      for (int i = 0; i < 4; ++i)
#pragma unroll
        for (int j = 0; j < 4; ++j)
          acc[i][j] = __builtin_amdgcn_mfma_f32_16x16x32_bf16(af[i], bfv[j], acc[i][j], 0, 0, 0);
    }
  };

  // prologue: stage tile 0 into buffer 0
#pragma unroll
  for (int p = 0; p < 4; ++p) {
    gload16(Ag + (size_t)(p * 32) * K, lA + p * 2048);
    gload16(Bg + (size_t)(p * 32) * K, lB + p * 2048);
  }
  __syncthreads();
  int cur = 0;
  for (int kt = 64; kt < K; kt += 64) {
    const int nxt = cur ^ 1;
    // issue next tile's loads BEFORE compute (latency hides under ds_read+MFMA)
#pragma unroll
    for (int p = 0; p < 4; ++p) {
      gload16(Ag + (size_t)(p * 32) * K + kt, lA + nxt * 8192 + p * 2048);
      gload16(Bg + (size_t)(p * 32) * K + kt, lB + nxt * 8192 + p * 2048);
    }
    compute(lsA + cur * 8192, lsB + cur * 8192);
    __syncthreads();  // drains vmcnt(0)+lgkmcnt(0): next buffer ready, cur consumed
    cur = nxt;
  }
  compute(lsA + cur * 8192, lsB + cur * 8192);  // tail tile

  // epilogue: C/D layout col=lane&15, row=(lane>>4)*4+q
  const int colb = n0 + wc * 64 + (lane & 15);
  const int rowb = m0 + wr * 64 + (lane >> 4) * 4;
#pragma unroll
  for (int j = 0; j < 4; ++j) {
    const int col = colb + j * 16;
    const float bv = bias ? bias[col] : 0.f;
#pragma unroll
    for (int i = 0; i < 4; ++i) {
#pragma unroll
      for (int q = 0; q < 4; ++q) {
        const float v = acc[i][j][q] * scale + bv;
        const size_t idx = (size_t)(rowb + i * 16 + q) * N + col;
        if (OUTF32) ((float*)Cp)[idx] = v;
        else        ((u16*)Cp)[idx]  = f2bf(v);
      }
    }
  }
}

// ---------------- masked row softmax, bf16 in-place -------------------------
__global__ __launch_bounds__(256) void k_softmax(
    u16* __restrict__ sc, const int* __restrict__ ccnt, int b)
{
  const int t = threadIdx.x, lane = t & 63, w = t >> 6;
  const int row = blockIdx.x;
  const int Cb = ccnt[b];
  u16* p = sc + (size_t)row * SS + t * 16;
  ushort8 v0 = *(ushort8*)p, v1 = *(ushort8*)(p + 8);
  float x[16];
#pragma unroll
  for (int e = 0; e < 8; ++e) { x[e] = bf2f(v0[e]); x[8 + e] = bf2f(v1[e]); }
  const int cb0 = t * 16;
  float m = -1e30f;
#pragma unroll
  for (int e = 0; e < 16; ++e) if (cb0 + e < Cb) m = fmaxf(m, x[e]);
#pragma unroll
  for (int off = 32; off; off >>= 1) m = fmaxf(m, __shfl_xor(m, off));
  __shared__ float red[4], red2[4];
  if (lane == 0) red[w] = m;
  __syncthreads();
  m = fmaxf(fmaxf(red[0], red[1]), fmaxf(red[2], red[3]));
  float ssum = 0.f;
#pragma unroll
  for (int e = 0; e < 16; ++e) {
    float ev = (cb0 + e < Cb) ? __expf(x[e] - m) : 0.f;
    x[e] = ev; ssum += ev;
  }
#pragma unroll
  for (int off = 32; off; off >>= 1) ssum += __shfl_xor(ssum, off);
  if (lane == 0) red2[w] = ssum;
  __syncthreads();
  ssum = red2[0] + red2[1] + red2[2] + red2[3];
  const float inv = 1.f / ssum;
#pragma unroll
  for (int e = 0; e < 8; ++e) { v0[e] = f2bf(x[e] * inv); v1[e] = f2bf(x[8 + e] * inv); }
  *(ushort8*)p = v0; *(ushort8*)(p + 8) = v1;
}

// ---------------- bf16 transpose v[b][c][d] -> vT[b][d][c] ------------------
__global__ __launch_bounds__(256) void k_transpose(
    const u16* __restrict__ v, u16* __restrict__ vt)
{
  __shared__ u16 ts[64][80];  // row stride 160B keeps 16B alignment
  const int t = threadIdx.x;
  const int d0 = blockIdx.x * 64, c0 = blockIdx.y * 64, b = blockIdx.z;
#pragma unroll
  for (int p = 0; p < 2; ++p) {
    const int idx = p * 256 + t, r = idx >> 3, cc = idx & 7;
    ushort8 val = *(const ushort8*)(v + ((size_t)b * SS + c0 + r) * DD + d0 + cc * 8);
    *(ushort8*)&ts[r][cc * 8] = val;
  }
  __syncthreads();
#pragma unroll
  for (int p = 0; p < 2; ++p) {
    const int idx = p * 256 + t, r = idx >> 3, cc = idx & 7;
    ushort8 o;
#pragma unroll
    for (int e = 0; e < 8; ++e) o[e] = ts[cc * 8 + e][r];
    *(ushort8*)(vt + ((size_t)b * DD + d0 + r) * SS + c0 + cc * 8) = o;
  }
}

// ---------------- loss finalize ---------------------------------------------
__global__ __launch_bounds__(256) void k_lossfin(
    const float* __restrict__ part, float* __restrict__ out)
{
  const int t = threadIdx.x, lane = t & 63, w = t >> 6;
  float s = 0.f;
  for (int i = t; i < 4096; i += 256) s += part[i];
#pragma unroll
  for (int off = 32; off; off >>= 1) s += __shfl_xor(s, off);
  __shared__ float r[4];
  if (lane == 0) r[w] = s;
  __syncthreads();
  if (t == 0) out[0] = (r[0] + r[1] + r[2] + r[3]) * (1.f / (NB * SS));
}

extern "C" void kernel_launch(void* const* d_in, const int* in_sizes, int n_in,
                              void* d_out, int out_size, void* d_ws, size_t ws_size,
                              hipStream_t stream) {
  const float* h  = (const float*)d_in[0];
  const int* plab = (const int*)d_in[1];
  const float* Wl = (const float*)d_in[2];
  const float* bl = (const float*)d_in[3];
  const float* Wq = (const float*)d_in[4];
  const float* bq = (const float*)d_in[5];
  const float* Wk = (const float*)d_in[6];
  const float* bk = (const float*)d_in[7];
  const float* Wv = (const float*)d_in[8];
  const float* bv = (const float*)d_in[9];
  const float* Wo = (const float*)d_in[10];
  const float* bo = (const float*)d_in[11];
  float* out = (float*)d_out;

  char* ws = (char*)d_ws;
  const size_t SZ = (size_t)NB * SS * DD * 2;  // 32 MB (bf16 [B*S, D])
  u16* h16      = (u16*)(ws + 0 * SZ);  // dead after q GEMM -> aliases scores
  u16* cemb     = (u16*)(ws + 1 * SZ);  // dead after k,v GEMM -> aliases attended
  u16* q        = (u16*)(ws + 2 * SZ);
  u16* kk       = (u16*)(ws + 3 * SZ);
  u16* vv       = (u16*)(ws + 4 * SZ);
  u16* vt       = (u16*)(ws + 5 * SZ);
  u16* Wt       = (u16*)(ws + 6 * SZ);                     // 4 x 1024x1024 bf16 = 8 MB
  char* ws2     = ws + 6 * SZ + (size_t)4 * 1024 * 1024 * 2;
  int* pred     = (int*)ws2;                               // 64 KB
  int* cstart   = (int*)(ws2 + 65536);                     // 4*(S+1) ints
  int* ccnt     = (int*)(ws2 + 65536 + 4 * (SS + 1) * 4);
  float* lossPart = (float*)(ws2 + 65536 + 4 * (SS + 1) * 4 + 64);
  u16* scores   = h16;   // per-batch [S,S] bf16 = 32 MB, alias (q GEMM completes first)
  u16* attended = cemb;  // [B*S, D] bf16, alias (k,v GEMMs complete first)

  k_logits<<<dim3(NB * SS / 4), 256, 0, stream>>>(h, plab, Wl, bl, h16, pred, lossPart);
  k_wconv<<<dim3(4 * 1024 * 1024 / 256), 256, 0, stream>>>(Wq, Wk, Wv, Wo, Wt);
  k_scan<<<dim3(NB), 256, 0, stream>>>(pred, cstart, ccnt);
  k_pool<<<dim3(NB * SS / 4), 256, 0, stream>>>(h, cstart, ccnt, cemb);

  gemm_nt<0><<<dim3(DD / 128, NB * SS / 128), 256, 0, stream>>>(
      h16, Wt, q, bq, 1.f, NB * SS, DD, DD);
  gemm_nt<0><<<dim3(DD / 128, NB * SS / 128), 256, 0, stream>>>(
      cemb, Wt + (1 << 20), kk, bk, 1.f, NB * SS, DD, DD);
  gemm_nt<0><<<dim3(DD / 128, NB * SS / 128), 256, 0, stream>>>(
      cemb, Wt + 2 * (1 << 20), vv, bv, 1.f, NB * SS, DD, DD);
  k_transpose<<<dim3(DD / 64, SS / 64, NB), 256, 0, stream>>>(vv, vt);

  const float scl = 1.f / 32.f;  // 1/sqrt(DC)
  for (int b = 0; b < NB; ++b) {
    gemm_nt<0><<<dim3(SS / 128, SS / 128), 256, 0, stream>>>(
        q + (size_t)b * SS * DD, kk + (size_t)b * SS * DD, scores, nullptr, scl, SS, SS, DD);
    k_softmax<<<dim3(SS), 256, 0, stream>>>(scores, ccnt, b);
    gemm_nt<0><<<dim3(DD / 128, SS / 128), 256, 0, stream>>>(
        scores, vt + (size_t)b * DD * SS, attended + (size_t)b * SS * DD, nullptr, 1.f, SS, DD, SS);
  }
  gemm_nt<1><<<dim3(DD / 128, NB * SS / 128), 256, 0, stream>>>(
      attended, Wt + 3 * (1 << 20), out, bo, 1.f, NB * SS, DD, DD);
  k_lossfin<<<dim3(1), 256, 0, stream>>>(lossPart, out + (size_t)NB * SS * DD);
}

// Round 4
// 640.083 us; speedup vs baseline: 1.4514x; 1.2758x over previous
//
#include <hip/hip_runtime.h>

typedef unsigned short u16;
typedef __attribute__((ext_vector_type(8))) short short8;
typedef __attribute__((ext_vector_type(8))) unsigned short ushort8;
typedef __attribute__((ext_vector_type(4))) unsigned short ushort4v;
typedef __attribute__((ext_vector_type(4))) float f32x4;

#define NB 4
#define SS 4096
#define DD 1024

__device__ __forceinline__ u16 f2bf(float x) {
  unsigned u = __builtin_bit_cast(unsigned, x);
  u = (u + 0x7FFFu + ((u >> 16) & 1u)) >> 16;
  return (u16)u;
}
__device__ __forceinline__ float bf2f(u16 b) {
  unsigned u = ((unsigned)b) << 16;
  return __builtin_bit_cast(float, u);
}
__device__ __forceinline__ void gload16(const void* g, void* l) {
  __builtin_amdgcn_global_load_lds((const __attribute__((address_space(1))) void*)g,
                                   (__attribute__((address_space(3))) void*)l, 16, 0, 0);
}
// bijective XCD-aware swizzle (m204)
__device__ __forceinline__ int xcd_swz(int bid, int nwg) {
  const int x = bid & 7, idx = bid >> 3;
  const int q = nwg >> 3, r = nwg & 7;
  return (x < r ? x * (q + 1) : r * (q + 1) + (x - r) * q) + idx;
}

// ---------------- kernel 1: logits (f32), loss partials, pred, h->bf16 -----
__global__ __launch_bounds__(256) void k_logits(
    const float* __restrict__ h, const int* __restrict__ lab,
    const float* __restrict__ Wl, const float* __restrict__ bl,
    u16* __restrict__ h16, int* __restrict__ pred, float* __restrict__ lossPart)
{
  const int t = threadIdx.x, w = t >> 6, lane = t & 63;
  const int tok = blockIdx.x * 4 + w;
  const float4* h4p = (const float4*)(h + (size_t)tok * DD);
  const float4* wl4 = (const float4*)Wl;
  float p0 = 0.f, p1 = 0.f, p2 = 0.f, p3 = 0.f;
#pragma unroll
  for (int i = 0; i < 4; ++i) {
    const int d = i * 256 + lane * 4;
    float4 hv = h4p[i * 64 + lane];
    ushort4v hb;
    hb[0] = f2bf(hv.x); hb[1] = f2bf(hv.y); hb[2] = f2bf(hv.z); hb[3] = f2bf(hv.w);
    *(ushort4v*)(h16 + (size_t)tok * DD + d) = hb;
    float4 w0 = wl4[d], w1 = wl4[d + 1], w2 = wl4[d + 2], w3 = wl4[d + 3];
    p0 += hv.x * w0.x + hv.y * w1.x + hv.z * w2.x + hv.w * w3.x;
    p1 += hv.x * w0.y + hv.y * w1.y + hv.z * w2.y + hv.w * w3.y;
    p2 += hv.x * w0.z + hv.y * w1.z + hv.z * w2.z + hv.w * w3.z;
    p3 += hv.x * w0.w + hv.y * w1.w + hv.z * w2.w + hv.w * w3.w;
  }
#pragma unroll
  for (int m = 32; m; m >>= 1) {
    p0 += __shfl_xor(p0, m); p1 += __shfl_xor(p1, m);
    p2 += __shfl_xor(p2, m); p3 += __shfl_xor(p3, m);
  }
  __shared__ float ls[4];
  if (lane == 0) {
    float l[4] = {p0 + bl[0], p1 + bl[1], p2 + bl[2], p3 + bl[3]};
    int bi = 0; float bv = l[0];
#pragma unroll
    for (int c = 1; c < 4; ++c) if (l[c] > bv) { bv = l[c]; bi = c; }
    pred[tok] = bi;
    float se = 0.f;
#pragma unroll
    for (int c = 0; c < 4; ++c) se += expf(l[c] - bv);
    float lse = bv + logf(se);
    ls[w] = lse - l[lab[tok]];
  }
  __syncthreads();
  if (t == 0) lossPart[blockIdx.x] = ls[0] + ls[1] + ls[2] + ls[3];
}

// ---------------- kernel 2: weights -> transposed bf16 ---------------------
__global__ __launch_bounds__(256) void k_wconv(
    const float* __restrict__ W0, const float* __restrict__ W1,
    const float* __restrict__ W2, const float* __restrict__ W3,
    u16* __restrict__ Wt)
{
  const int gid = blockIdx.x * 256 + threadIdx.x;
  const int mat = gid >> 20;
  const int rem = gid & ((1 << 20) - 1);
  const int n = rem >> 10, k = rem & 1023;
  const float* W = (mat == 0) ? W0 : (mat == 1) ? W1 : (mat == 2) ? W2 : W3;
  Wt[((size_t)mat << 20) + (size_t)n * 1024 + k] = f2bf(W[(size_t)k * 1024 + n]);
}

// ---------------- kernel 3: BIOS chunk scan (1 block / batch) --------------
__global__ __launch_bounds__(256) void k_scan(
    const int* __restrict__ pred, int* __restrict__ cstart, int* __restrict__ ccnt)
{
  const int b = blockIdx.x, t = threadIdx.x;
  const int4* p4 = (const int4*)(pred + (size_t)b * SS);
  int labv[16];
#pragma unroll
  for (int i = 0; i < 4; ++i) {
    int4 v = p4[t * 4 + i];
    labv[i * 4 + 0] = v.x; labv[i * 4 + 1] = v.y;
    labv[i * 4 + 2] = v.z; labv[i * 4 + 3] = v.w;
  }
  int A = 0, Bc = 1;
#pragma unroll
  for (int e = 0; e < 16; ++e) {
    int a = (labv[e] == 0), bb = (labv[e] == 1);
    A = a | (bb & A);
    Bc = bb & Bc;
  }
  __shared__ int sA[256], sB[256], sC[256];
  sA[t] = A; sB[t] = Bc;
  __syncthreads();
  for (int off = 1; off < 256; off <<= 1) {
    int pa = 0, pb = 1;
    if (t >= off) { pa = sA[t - off]; pb = sB[t - off]; }
    __syncthreads();
    A = A | (Bc & pa); Bc = Bc & pb;
    sA[t] = A; sB[t] = Bc;
    __syncthreads();
  }
  const int extIn = (t == 0) ? 0 : sA[t - 1];
  int ext = extIn, nst = 0;
#pragma unroll
  for (int e = 0; e < 16; ++e) {
    int cont = (labv[e] == 1) & ext;
    nst += !cont;
    ext = (labv[e] == 0) | cont;
  }
  sC[t] = nst;
  __syncthreads();
  int tot = nst;
  for (int off = 1; off < 256; off <<= 1) {
    int pc = 0;
    if (t >= off) pc = sC[t - off];
    __syncthreads();
    tot += pc;
    sC[t] = tot;
    __syncthreads();
  }
  const int base = tot - nst;
  const int total = sC[255];
  if (t == 0) { ccnt[b] = total; cstart[b * (SS + 1) + total] = SS; }
  ext = extIn; int id = base;
#pragma unroll
  for (int e = 0; e < 16; ++e) {
    int cont = (labv[e] == 1) & ext;
    if (!cont) cstart[b * (SS + 1) + id++] = t * 16 + e;
    ext = (labv[e] == 0) | cont;
  }
}

// ---------------- kernel 4: segment-mean pooling (1 wave / chunk) ----------
__global__ __launch_bounds__(256) void k_pool(
    const float* __restrict__ h, const int* __restrict__ cstart,
    const int* __restrict__ ccnt, u16* __restrict__ cemb)
{
  const int t = threadIdx.x, w = t >> 6, lane = t & 63;
  const int gw = blockIdx.x * 4 + w;
  const int b = gw >> 12, c = gw & (SS - 1);
  u16* out = cemb + (size_t)gw * DD + lane * 16;
  if (c >= ccnt[b]) {
    ushort8 z = {0, 0, 0, 0, 0, 0, 0, 0};
    *(ushort8*)out = z; *(ushort8*)(out + 8) = z;
    return;
  }
  const int s0 = cstart[b * (SS + 1) + c], s1 = cstart[b * (SS + 1) + c + 1];
  float acc[16] = {};
  for (int s = s0; s < s1; ++s) {
    const float4* hp = (const float4*)(h + ((size_t)b * SS + s) * DD + lane * 16);
#pragma unroll
    for (int ii = 0; ii < 4; ++ii) {
      float4 v = hp[ii];
      acc[ii * 4 + 0] += v.x; acc[ii * 4 + 1] += v.y;
      acc[ii * 4 + 2] += v.z; acc[ii * 4 + 3] += v.w;
    }
  }
  const float inv = 1.f / (float)(s1 - s0);
  ushort8 o0, o1;
#pragma unroll
  for (int e = 0; e < 8; ++e) { o0[e] = f2bf(acc[e] * inv); o1[e] = f2bf(acc[8 + e] * inv); }
  *(ushort8*)out = o0; *(ushort8*)(out + 8) = o1;
}

// ---------------- 256x256 NT bf16 GEMM, BK=64, 8 waves, counted-vmcnt pipeline
// C_z[m,n] = scale*sum_k A_z[m,k]*B_z[n,k] + bias[n];  A_z,C_z per-z pointers,
// B_z = Bt + z*strideB. XOR-swizzled LDS (conflict-free, verified r3).
// Pipeline: 2 buffers; stage tile i+2 into buf[cur] after end-of-read barrier;
// top-of-iter s_waitcnt vmcnt(8) (never 0 mid-loop) + barrier. T4 per m218.
template <int OUTF32>
__global__ __launch_bounds__(512, 2) void gemm256(
    const u16* __restrict__ A0, const u16* __restrict__ A1,
    const u16* __restrict__ A2, const u16* __restrict__ A3,
    const u16* __restrict__ Bt, long strideB,
    void* __restrict__ C0, void* __restrict__ C1,
    void* __restrict__ C2, void* __restrict__ C3,
    const float* __restrict__ bias, float scale, int M, int N, int K)
{
  __shared__ u16 sA[2][256 * 64], sB[2][256 * 64];  // 128 KB
  const int t = threadIdx.x, lane = t & 63, w = t >> 6;
  const int wr = w >> 2, wc = w & 3;
  const int z = blockIdx.z;
  const u16* A = (z == 0) ? A0 : (z == 1) ? A1 : (z == 2) ? A2 : A3;
  void* Cp    = (z == 0) ? C0 : (z == 1) ? C1 : (z == 2) ? C2 : C3;
  const u16* B = Bt + (size_t)z * strideB;
  const int bid = blockIdx.y * gridDim.x + blockIdx.x;
  const int swz = xcd_swz(bid, gridDim.x * gridDim.y);
  const int m0 = (swz / gridDim.x) * 256, n0 = (swz % gridDim.x) * 256;

  f32x4 acc[8][4];
#pragma unroll
  for (int i = 0; i < 8; ++i)
#pragma unroll
    for (int j = 0; j < 4; ++j) acc[i][j] = (f32x4){0.f, 0.f, 0.f, 0.f};

  // staging: 8 gload16/thread per K-tile (A groups 0-3, B groups 0-3).
  // source chunk XOR'd with dest row&7 (involution); dest linear (rule 21).
  const int trow = t >> 3;
  const int schunk = ((t & 7) ^ (trow & 7)) * 8;
  const u16* Ag = A + (size_t)(m0 + trow) * K + schunk;
  const u16* Bg = B + (size_t)(n0 + trow) * K + schunk;
  u16* lA = &sA[0][0] + t * 8;
  u16* lB = &sB[0][0] + t * 8;
  auto stage = [&](int c, int kt) {
#pragma unroll
    for (int g = 0; g < 4; ++g)
      gload16(Ag + (size_t)(g * 64) * K + kt, lA + c * 16384 + g * 4096);
#pragma unroll
    for (int g = 0; g < 4; ++g)
      gload16(Bg + (size_t)(g * 64) * K + kt, lB + c * 16384 + g * 4096);
  };

  const int lrow = lane & 15, hi = lane >> 4, sx = lrow & 7;
  auto compute = [&](int c) {
    const u16* bA = &sA[c][0];
    const u16* bB = &sB[c][0];
#pragma unroll
    for (int ks = 0; ks < 2; ++ks) {
      const int co = ((ks * 4 + hi) ^ sx) * 8;
      short8 af[8], bf[4];
#pragma unroll
      for (int m = 0; m < 8; ++m)
        af[m] = *(const short8*)(bA + (wr * 128 + m * 16 + lrow) * 64 + co);
#pragma unroll
      for (int n = 0; n < 4; ++n)
        bf[n] = *(const short8*)(bB + (wc * 64 + n * 16 + lrow) * 64 + co);
#pragma unroll
      for (int m = 0; m < 8; ++m)
#pragma unroll
        for (int n = 0; n < 4; ++n)
          acc[m][n] = __builtin_amdgcn_mfma_f32_16x16x32_bf16(af[m], bf[n], acc[m][n], 0, 0, 0);
    }
  };

  const int NT = K >> 6;
  stage(0, 0);
  if (NT > 1) { stage(1, 64); asm volatile("s_waitcnt vmcnt(8)" ::: "memory"); }
  else        { asm volatile("s_waitcnt vmcnt(0)" ::: "memory"); }
  __builtin_amdgcn_s_barrier();
  asm volatile("" ::: "memory");
  for (int i = 0; i < NT; ++i) {
    const int cur = i & 1;
    compute(cur);
    asm volatile("" ::: "memory");
    if (i + 2 < NT) {
      __builtin_amdgcn_s_barrier();       // all waves done reading buf[cur]
      asm volatile("" ::: "memory");
      stage(cur, (i + 2) * 64);           // tile i+2 -> buf[cur]
    }
    if (i + 1 < NT) {
      if (i + 2 < NT) asm volatile("s_waitcnt vmcnt(8)" ::: "memory");  // tile i+1 landed
      else            asm volatile("s_waitcnt vmcnt(0)" ::: "memory");  // last tile: drain
      __builtin_amdgcn_s_barrier();       // buf[cur^1] visible to all
      asm volatile("" ::: "memory");
    }
  }

  // epilogue: per frag, col=lane&15, row=(lane>>4)*4+q
  const int colb = n0 + wc * 64 + (lane & 15);
  const int rowb = m0 + wr * 128 + (lane >> 4) * 4;
#pragma unroll
  for (int n = 0; n < 4; ++n) {
    const int col = colb + n * 16;
    const float bv = bias ? bias[col] : 0.f;
#pragma unroll
    for (int m = 0; m < 8; ++m) {
#pragma unroll
      for (int qx = 0; qx < 4; ++qx) {
        const float v = acc[m][n][qx] * scale + bv;
        const size_t idx = (size_t)(rowb + m * 16 + qx) * N + col;
        if (OUTF32) ((float*)Cp)[idx] = v;
        else        ((u16*)Cp)[idx]  = f2bf(v);
      }
    }
  }
}

// ---------------- masked row softmax, bf16 in-place, z-folded ---------------
__global__ __launch_bounds__(256) void k_softmax(
    u16* __restrict__ s0, u16* __restrict__ s1,
    u16* __restrict__ s2, u16* __restrict__ s3, const int* __restrict__ ccnt)
{
  const int t = threadIdx.x, lane = t & 63, w = t >> 6;
  const int row = blockIdx.x, b = blockIdx.y;
  u16* sc = (b == 0) ? s0 : (b == 1) ? s1 : (b == 2) ? s2 : s3;
  const int Cb = ccnt[b];
  u16* p = sc + (size_t)row * SS + t * 16;
  ushort8 v0 = *(ushort8*)p, v1 = *(ushort8*)(p + 8);
  float x[16];
#pragma unroll
  for (int e = 0; e < 8; ++e) { x[e] = bf2f(v0[e]); x[8 + e] = bf2f(v1[e]); }
  const int cb0 = t * 16;
  float m = -1e30f;
#pragma unroll
  for (int e = 0; e < 16; ++e) if (cb0 + e < Cb) m = fmaxf(m, x[e]);
#pragma unroll
  for (int off = 32; off; off >>= 1) m = fmaxf(m, __shfl_xor(m, off));
  __shared__ float red[4], red2[4];
  if (lane == 0) red[w] = m;
  __syncthreads();
  m = fmaxf(fmaxf(red[0], red[1]), fmaxf(red[2], red[3]));
  float ssum = 0.f;
#pragma unroll
  for (int e = 0; e < 16; ++e) {
    float ev = (cb0 + e < Cb) ? __expf(x[e] - m) : 0.f;
    x[e] = ev; ssum += ev;
  }
#pragma unroll
  for (int off = 32; off; off >>= 1) ssum += __shfl_xor(ssum, off);
  if (lane == 0) red2[w] = ssum;
  __syncthreads();
  ssum = red2[0] + red2[1] + red2[2] + red2[3];
  const float inv = 1.f / ssum;
#pragma unroll
  for (int e = 0; e < 8; ++e) { v0[e] = f2bf(x[e] * inv); v1[e] = f2bf(x[8 + e] * inv); }
  *(ushort8*)p = v0; *(ushort8*)(p + 8) = v1;
}

// ---------------- bf16 transpose v[b][c][d] -> vT[b][d][c] ------------------
__global__ __launch_bounds__(256) void k_transpose(
    const u16* __restrict__ v, u16* __restrict__ vt)
{
  __shared__ u16 ts[64][80];
  const int t = threadIdx.x;
  const int d0 = blockIdx.x * 64, c0 = blockIdx.y * 64, b = blockIdx.z;
#pragma unroll
  for (int p = 0; p < 2; ++p) {
    const int idx = p * 256 + t, r = idx >> 3, cc = idx & 7;
    ushort8 val = *(const ushort8*)(v + ((size_t)b * SS + c0 + r) * DD + d0 + cc * 8);
    *(ushort8*)&ts[r][cc * 8] = val;
  }
  __syncthreads();
#pragma unroll
  for (int p = 0; p < 2; ++p) {
    const int idx = p * 256 + t, r = idx >> 3, cc = idx & 7;
    ushort8 o;
#pragma unroll
    for (int e = 0; e < 8; ++e) o[e] = ts[cc * 8 + e][r];
    *(ushort8*)(vt + ((size_t)b * DD + d0 + r) * SS + c0 + cc * 8) = o;
  }
}

// ---------------- loss finalize ---------------------------------------------
__global__ __launch_bounds__(256) void k_lossfin(
    const float* __restrict__ part, float* __restrict__ out)
{
  const int t = threadIdx.x, lane = t & 63, w = t >> 6;
  float s = 0.f;
  for (int i = t; i < 4096; i += 256) s += part[i];
#pragma unroll
  for (int off = 32; off; off >>= 1) s += __shfl_xor(s, off);
  __shared__ float r[4];
  if (lane == 0) r[w] = s;
  __syncthreads();
  if (t == 0) out[0] = (r[0] + r[1] + r[2] + r[3]) * (1.f / (NB * SS));
}

extern "C" void kernel_launch(void* const* d_in, const int* in_sizes, int n_in,
                              void* d_out, int out_size, void* d_ws, size_t ws_size,
                              hipStream_t stream) {
  const float* h  = (const float*)d_in[0];
  const int* plab = (const int*)d_in[1];
  const float* Wl = (const float*)d_in[2];
  const float* bl = (const float*)d_in[3];
  const float* Wq = (const float*)d_in[4];
  const float* bq = (const float*)d_in[5];
  const float* Wk = (const float*)d_in[6];
  const float* bk = (const float*)d_in[7];
  const float* Wv = (const float*)d_in[8];
  const float* bv = (const float*)d_in[9];
  const float* Wo = (const float*)d_in[10];
  const float* bo = (const float*)d_in[11];
  float* out = (float*)d_out;

  char* ws = (char*)d_ws;
  const size_t SZ = (size_t)NB * SS * DD * 2;  // 32 MB
  const size_t SD = (size_t)SS * DD;           // per-batch elems
  u16* h16      = (u16*)(ws + 0 * SZ);  // dead after q GEMM -> scores[2]
  u16* cemb     = (u16*)(ws + 1 * SZ);  // dead after k,v GEMM -> scores[3]
  u16* q        = (u16*)(ws + 2 * SZ);
  u16* kk       = (u16*)(ws + 3 * SZ);
  u16* vv       = (u16*)(ws + 4 * SZ);  // dead after transpose -> attended
  u16* vt       = (u16*)(ws + 5 * SZ);
  u16* Wt       = (u16*)(ws + 6 * SZ);  // 8 MB
  char* ws2     = ws + 6 * SZ + (size_t)4 * 1024 * 1024 * 2;
  int* pred     = (int*)ws2;
  int* cstart   = (int*)(ws2 + 65536);
  int* ccnt     = (int*)(ws2 + 65536 + 4 * (SS + 1) * 4);
  float* lossPart = (float*)(ws2 + 65536 + 4 * (SS + 1) * 4 + 64);
  // scores[b]: [S,S] bf16, 32 MB each. s0,s1 borrow d_out (64 MB, dead until
  // the final out-GEMM overwrites it); s2,s3 reuse dead h16/cemb.
  u16* s0 = (u16*)d_out;
  u16* s1 = (u16*)d_out + (size_t)SS * SS;
  u16* s2 = h16;
  u16* s3 = cemb;
  u16* att = vv;

  k_logits<<<dim3(NB * SS / 4), 256, 0, stream>>>(h, plab, Wl, bl, h16, pred, lossPart);
  k_wconv<<<dim3(4 * 1024 * 1024 / 256), 256, 0, stream>>>(Wq, Wk, Wv, Wo, Wt);
  k_scan<<<dim3(NB), 256, 0, stream>>>(pred, cstart, ccnt);
  k_pool<<<dim3(NB * SS / 4), 256, 0, stream>>>(h, cstart, ccnt, cemb);

  gemm256<0><<<dim3(DD / 256, NB * SS / 256, 1), 512, 0, stream>>>(
      h16, h16, h16, h16, Wt, 0, q, q, q, q, bq, 1.f, NB * SS, DD, DD);
  gemm256<0><<<dim3(DD / 256, NB * SS / 256, 1), 512, 0, stream>>>(
      cemb, cemb, cemb, cemb, Wt + (1 << 20), 0, kk, kk, kk, kk, bk, 1.f, NB * SS, DD, DD);
  gemm256<0><<<dim3(DD / 256, NB * SS / 256, 1), 512, 0, stream>>>(
      cemb, cemb, cemb, cemb, Wt + 2 * (1 << 20), 0, vv, vv, vv, vv, bv, 1.f, NB * SS, DD, DD);
  k_transpose<<<dim3(DD / 64, SS / 64, NB), 256, 0, stream>>>(vv, vt);

  const float scl = 1.f / 32.f;  // 1/sqrt(DC)
  gemm256<0><<<dim3(SS / 256, SS / 256, NB), 512, 0, stream>>>(
      q, q + SD, q + 2 * SD, q + 3 * SD, kk, (long)SD,
      s0, s1, s2, s3, nullptr, scl, SS, SS, DD);
  k_softmax<<<dim3(SS, NB), 256, 0, stream>>>(s0, s1, s2, s3, ccnt);
  gemm256<0><<<dim3(DD / 256, SS / 256, NB), 512, 0, stream>>>(
      s0, s1, s2, s3, vt, (long)SD,
      att, att + SD, att + 2 * SD, att + 3 * SD, nullptr, 1.f, SS, DD, SS);
  gemm256<1><<<dim3(DD / 256, NB * SS / 256, 1), 512, 0, stream>>>(
      att, att, att, att, Wt + 3 * (1 << 20), 0, out, out, out, out, bo, 1.f, NB * SS, DD, DD);
  k_lossfin<<<dim3(1), 256, 0, stream>>>(lossPart, out + (size_t)NB * SS * DD);
}

// Round 5
// 535.219 us; speedup vs baseline: 1.7358x; 1.1959x over previous
//
#include <hip/hip_runtime.h>

typedef unsigned short u16;
typedef __attribute__((ext_vector_type(8))) short short8;
typedef __attribute__((ext_vector_type(8))) unsigned short ushort8;
typedef __attribute__((ext_vector_type(4))) unsigned short ushort4v;
typedef __attribute__((ext_vector_type(4))) float f32x4;

#define NB 4
#define SS 4096
#define DD 1024
#define CFENCE asm volatile("" ::: "memory")

__device__ __forceinline__ u16 f2bf(float x) {
  unsigned u = __builtin_bit_cast(unsigned, x);
  u = (u + 0x7FFFu + ((u >> 16) & 1u)) >> 16;
  return (u16)u;
}
__device__ __forceinline__ float bf2f(u16 b) {
  unsigned u = ((unsigned)b) << 16;
  return __builtin_bit_cast(float, u);
}
__device__ __forceinline__ void gload16(const void* g, void* l) {
  __builtin_amdgcn_global_load_lds((const __attribute__((address_space(1))) void*)g,
                                   (__attribute__((address_space(3))) void*)l, 16, 0, 0);
}
// bijective XCD-aware swizzle (m204)
__device__ __forceinline__ int xcd_swz(int bid, int nwg) {
  const int x = bid & 7, idx = bid >> 3;
  const int q = nwg >> 3, r = nwg & 7;
  return (x < r ? x * (q + 1) : r * (q + 1) + (x - r) * q) + idx;
}

// ---------------- kernel 1: logits (f32), loss partials, pred, h->bf16 -----
__global__ __launch_bounds__(256) void k_logits(
    const float* __restrict__ h, const int* __restrict__ lab,
    const float* __restrict__ Wl, const float* __restrict__ bl,
    u16* __restrict__ h16, int* __restrict__ pred, float* __restrict__ lossPart)
{
  const int t = threadIdx.x, w = t >> 6, lane = t & 63;
  const int tok = blockIdx.x * 4 + w;
  const float4* h4p = (const float4*)(h + (size_t)tok * DD);
  const float4* wl4 = (const float4*)Wl;
  float p0 = 0.f, p1 = 0.f, p2 = 0.f, p3 = 0.f;
#pragma unroll
  for (int i = 0; i < 4; ++i) {
    const int d = i * 256 + lane * 4;
    float4 hv = h4p[i * 64 + lane];
    ushort4v hb;
    hb[0] = f2bf(hv.x); hb[1] = f2bf(hv.y); hb[2] = f2bf(hv.z); hb[3] = f2bf(hv.w);
    *(ushort4v*)(h16 + (size_t)tok * DD + d) = hb;
    float4 w0 = wl4[d], w1 = wl4[d + 1], w2 = wl4[d + 2], w3 = wl4[d + 3];
    p0 += hv.x * w0.x + hv.y * w1.x + hv.z * w2.x + hv.w * w3.x;
    p1 += hv.x * w0.y + hv.y * w1.y + hv.z * w2.y + hv.w * w3.y;
    p2 += hv.x * w0.z + hv.y * w1.z + hv.z * w2.z + hv.w * w3.z;
    p3 += hv.x * w0.w + hv.y * w1.w + hv.z * w2.w + hv.w * w3.w;
  }
#pragma unroll
  for (int m = 32; m; m >>= 1) {
    p0 += __shfl_xor(p0, m); p1 += __shfl_xor(p1, m);
    p2 += __shfl_xor(p2, m); p3 += __shfl_xor(p3, m);
  }
  __shared__ float ls[4];
  if (lane == 0) {
    float l[4] = {p0 + bl[0], p1 + bl[1], p2 + bl[2], p3 + bl[3]};
    int bi = 0; float bv = l[0];
#pragma unroll
    for (int c = 1; c < 4; ++c) if (l[c] > bv) { bv = l[c]; bi = c; }
    pred[tok] = bi;
    float se = 0.f;
#pragma unroll
    for (int c = 0; c < 4; ++c) se += expf(l[c] - bv);
    float lse = bv + logf(se);
    ls[w] = lse - l[lab[tok]];
  }
  __syncthreads();
  if (t == 0) lossPart[blockIdx.x] = ls[0] + ls[1] + ls[2] + ls[3];
}

// ---------------- kernel 2: weights -> transposed bf16 ---------------------
__global__ __launch_bounds__(256) void k_wconv(
    const float* __restrict__ W0, const float* __restrict__ W1,
    const float* __restrict__ W2, const float* __restrict__ W3,
    u16* __restrict__ Wt)
{
  const int gid = blockIdx.x * 256 + threadIdx.x;
  const int mat = gid >> 20;
  const int rem = gid & ((1 << 20) - 1);
  const int n = rem >> 10, k = rem & 1023;
  const float* W = (mat == 0) ? W0 : (mat == 1) ? W1 : (mat == 2) ? W2 : W3;
  Wt[((size_t)mat << 20) + (size_t)n * 1024 + k] = f2bf(W[(size_t)k * 1024 + n]);
}

// ---------------- kernel 3: BIOS chunk scan (1 block / batch) --------------
__global__ __launch_bounds__(256) void k_scan(
    const int* __restrict__ pred, int* __restrict__ cstart, int* __restrict__ ccnt)
{
  const int b = blockIdx.x, t = threadIdx.x;
  const int4* p4 = (const int4*)(pred + (size_t)b * SS);
  int labv[16];
#pragma unroll
  for (int i = 0; i < 4; ++i) {
    int4 v = p4[t * 4 + i];
    labv[i * 4 + 0] = v.x; labv[i * 4 + 1] = v.y;
    labv[i * 4 + 2] = v.z; labv[i * 4 + 3] = v.w;
  }
  int A = 0, Bc = 1;
#pragma unroll
  for (int e = 0; e < 16; ++e) {
    int a = (labv[e] == 0), bb = (labv[e] == 1);
    A = a | (bb & A);
    Bc = bb & Bc;
  }
  __shared__ int sA[256], sB[256], sC[256];
  sA[t] = A; sB[t] = Bc;
  __syncthreads();
  for (int off = 1; off < 256; off <<= 1) {
    int pa = 0, pb = 1;
    if (t >= off) { pa = sA[t - off]; pb = sB[t - off]; }
    __syncthreads();
    A = A | (Bc & pa); Bc = Bc & pb;
    sA[t] = A; sB[t] = Bc;
    __syncthreads();
  }
  const int extIn = (t == 0) ? 0 : sA[t - 1];
  int ext = extIn, nst = 0;
#pragma unroll
  for (int e = 0; e < 16; ++e) {
    int cont = (labv[e] == 1) & ext;
    nst += !cont;
    ext = (labv[e] == 0) | cont;
  }
  sC[t] = nst;
  __syncthreads();
  int tot = nst;
  for (int off = 1; off < 256; off <<= 1) {
    int pc = 0;
    if (t >= off) pc = sC[t - off];
    __syncthreads();
    tot += pc;
    sC[t] = tot;
    __syncthreads();
  }
  const int base = tot - nst;
  const int total = sC[255];
  if (t == 0) { ccnt[b] = total; cstart[b * (SS + 1) + total] = SS; }
  ext = extIn; int id = base;
#pragma unroll
  for (int e = 0; e < 16; ++e) {
    int cont = (labv[e] == 1) & ext;
    if (!cont) cstart[b * (SS + 1) + id++] = t * 16 + e;
    ext = (labv[e] == 0) | cont;
  }
}

// ---------------- kernel 4: segment-mean pooling (1 wave / chunk) ----------
__global__ __launch_bounds__(256) void k_pool(
    const float* __restrict__ h, const int* __restrict__ cstart,
    const int* __restrict__ ccnt, u16* __restrict__ cemb)
{
  const int t = threadIdx.x, w = t >> 6, lane = t & 63;
  const int gw = blockIdx.x * 4 + w;
  const int b = gw >> 12, c = gw & (SS - 1);
  u16* out = cemb + (size_t)gw * DD + lane * 16;
  if (c >= ccnt[b]) {
    ushort8 z = {0, 0, 0, 0, 0, 0, 0, 0};
    *(ushort8*)out = z; *(ushort8*)(out + 8) = z;
    return;
  }
  const int s0 = cstart[b * (SS + 1) + c], s1 = cstart[b * (SS + 1) + c + 1];
  float acc[16] = {};
  for (int s = s0; s < s1; ++s) {
    const float4* hp = (const float4*)(h + ((size_t)b * SS + s) * DD + lane * 16);
#pragma unroll
    for (int ii = 0; ii < 4; ++ii) {
      float4 v = hp[ii];
      acc[ii * 4 + 0] += v.x; acc[ii * 4 + 1] += v.y;
      acc[ii * 4 + 2] += v.z; acc[ii * 4 + 3] += v.w;
    }
  }
  const float inv = 1.f / (float)(s1 - s0);
  ushort8 o0, o1;
#pragma unroll
  for (int e = 0; e < 8; ++e) { o0[e] = f2bf(acc[e] * inv); o1[e] = f2bf(acc[8 + e] * inv); }
  *(ushort8*)out = o0; *(ushort8*)(out + 8) = o1;
}

// ---------------- 256x256 NT bf16 GEMM, BK=64, 8 waves, 4-phase interleave --
// Per K-tile: gray-code quadrants (mh,nh)=(0,0),(0,1),(1,0),(1,1), 16 MFMA each,
// each LDS region read in exactly one phase (A-mh0@ph1, B-nh0@ph1, B-nh1@ph2,
// A-mh1@ph3; B kept in regs). Staging halves (2x gload_lds each):
//   ph1: SA1(j+1)->buf^1   [region last read: iter j-1 ph3 -> safe]
//   ph2: SA0(j+2)->buf     [last read: this iter ph1 -> safe]
//   ph3: SB0(j+2)->buf     [last read: ph1 -> safe]
//   ph4: SB1(j+2)->buf     [last read: ph2 -> safe]
// Gate once/iter before final barrier: vmcnt(6) guarantees tile j+1 landed
// (3 half-tiles stay in flight); vmcnt(0) at j==NT-2; no gate on last iter.
template <int OUTF32>
__global__ __launch_bounds__(512, 2) void gemm256(
    const u16* __restrict__ A0, const u16* __restrict__ A1,
    const u16* __restrict__ A2, const u16* __restrict__ A3,
    const u16* __restrict__ Bt, long strideB,
    void* __restrict__ C0, void* __restrict__ C1,
    void* __restrict__ C2, void* __restrict__ C3,
    const float* __restrict__ bias, float scale, int M, int N, int K)
{
  __shared__ u16 lds[65536];  // 128 KB: A dbuf (32K u16) | B dbuf; C-tile overlay
  u16* ldsA = lds;
  u16* ldsB = lds + 32768;
  const int t = threadIdx.x, lane = t & 63, w = t >> 6;
  const int wr = w >> 2, wc = w & 3;
  const int z = blockIdx.z;
  const u16* A = (z == 0) ? A0 : (z == 1) ? A1 : (z == 2) ? A2 : A3;
  void* Cp    = (z == 0) ? C0 : (z == 1) ? C1 : (z == 2) ? C2 : C3;
  const u16* B = Bt + (size_t)z * strideB;
  const int bid = blockIdx.y * gridDim.x + blockIdx.x;
  const int swz = xcd_swz(bid, gridDim.x * gridDim.y);
  const int m0 = (swz / gridDim.x) * 256, n0 = (swz % gridDim.x) * 256;

  f32x4 acc[8][4];
#pragma unroll
  for (int i = 0; i < 8; ++i)
#pragma unroll
    for (int j = 0; j < 4; ++j) acc[i][j] = (f32x4){0.f, 0.f, 0.f, 0.f};

  const int trow = t >> 3;
  const u16* Ag = A + (size_t)(m0 + trow) * K + ((t & 7) ^ (trow & 7)) * 8;
  const u16* Bg = B + (size_t)(n0 + trow) * K + ((t & 7) ^ (trow & 7)) * 8;
  u16* dA = ldsA + t * 8;
  u16* dB = ldsB + t * 8;

#define STG_A0(BUF, KT) { gload16(Ag + (size_t)(KT),            dA + (BUF) * 16384 + 0 * 4096); \
                          gload16(Ag + (size_t)128 * K + (KT),  dA + (BUF) * 16384 + 2 * 4096); }
#define STG_A1(BUF, KT) { gload16(Ag + (size_t)64 * K + (KT),   dA + (BUF) * 16384 + 1 * 4096); \
                          gload16(Ag + (size_t)192 * K + (KT),  dA + (BUF) * 16384 + 3 * 4096); }
#define STG_B0(BUF, KT) { gload16(Bg + (size_t)(KT),            dB + (BUF) * 16384 + 0 * 4096); \
                          gload16(Bg + (size_t)64 * K + (KT),   dB + (BUF) * 16384 + 1 * 4096); }
#define STG_B1(BUF, KT) { gload16(Bg + (size_t)128 * K + (KT),  dB + (BUF) * 16384 + 2 * 4096); \
                          gload16(Bg + (size_t)192 * K + (KT),  dB + (BUF) * 16384 + 3 * 4096); }
#define MFMA16(MH, NH, BF) \
  { _Pragma("unroll") for (int ks = 0; ks < 2; ++ks) \
    _Pragma("unroll") for (int mi = 0; mi < 4; ++mi) \
      _Pragma("unroll") for (int ni = 0; ni < 2; ++ni) \
        acc[(MH) * 4 + mi][(NH) * 2 + ni] = __builtin_amdgcn_mfma_f32_16x16x32_bf16( \
            af[mi][ks], BF[ni][ks], acc[(MH) * 4 + mi][(NH) * 2 + ni], 0, 0, 0); }

  const int lrow = lane & 15, hi = lane >> 4;
  const int co0 = (hi ^ (lrow & 7)) * 8;
  const int co1 = ((4 + hi) ^ (lrow & 7)) * 8;

  const int NT = K >> 6;
  // prologue: tile0 {A0,B0,B1,A1}, tile1 {A0,B0,B1}; SA1(1) comes at iter0 ph1
  STG_A0(0, 0); STG_B0(0, 0); STG_B1(0, 0); STG_A1(0, 0);
  if (NT > 1) { STG_A0(1, 64); STG_B0(1, 64); STG_B1(1, 64); }
  if (NT > 1) asm volatile("s_waitcnt vmcnt(6)" ::: "memory");  // tile0 landed
  else        asm volatile("s_waitcnt vmcnt(0)" ::: "memory");
  __builtin_amdgcn_s_barrier();
  CFENCE;

  for (int j = 0; j < NT; ++j) {
    const int cur = j & 1;
    const u16* bA = ldsA + cur * 16384;
    const u16* bB = ldsB + cur * 16384;
    const int kt1 = (j + 1) << 6, kt2 = (j + 2) << 6;
    short8 af[4][2], b0[2][2], b1[2][2];
    // ---- ph1 (mh0,nh0): read A-mh0 (8) + B-nh0 (4); stage SA1(j+1)
#pragma unroll
    for (int mi = 0; mi < 4; ++mi) {
      af[mi][0] = *(const short8*)(bA + (wr * 128 + mi * 16 + lrow) * 64 + co0);
      af[mi][1] = *(const short8*)(bA + (wr * 128 + mi * 16 + lrow) * 64 + co1);
    }
#pragma unroll
    for (int ni = 0; ni < 2; ++ni) {
      b0[ni][0] = *(const short8*)(bB + (wc * 32 + ni * 16 + lrow) * 64 + co0);
      b0[ni][1] = *(const short8*)(bB + (wc * 32 + ni * 16 + lrow) * 64 + co1);
    }
    if (j + 1 < NT) STG_A1(cur ^ 1, kt1);
    CFENCE;
    __builtin_amdgcn_s_barrier();
    __builtin_amdgcn_s_setprio(1);
    MFMA16(0, 0, b0);
    __builtin_amdgcn_s_setprio(0);
    __builtin_amdgcn_sched_barrier(0);
    __builtin_amdgcn_s_barrier();
    CFENCE;
    // ---- ph2 (mh0,nh1): read B-nh1 (4); stage SA0(j+2)
#pragma unroll
    for (int ni = 0; ni < 2; ++ni) {
      b1[ni][0] = *(const short8*)(bB + (128 + wc * 32 + ni * 16 + lrow) * 64 + co0);
      b1[ni][1] = *(const short8*)(bB + (128 + wc * 32 + ni * 16 + lrow) * 64 + co1);
    }
    if (j + 2 < NT) STG_A0(cur, kt2);
    CFENCE;
    __builtin_amdgcn_s_barrier();
    __builtin_amdgcn_s_setprio(1);
    MFMA16(0, 1, b1);
    __builtin_amdgcn_s_setprio(0);
    __builtin_amdgcn_sched_barrier(0);
    __builtin_amdgcn_s_barrier();
    CFENCE;
    // ---- ph3 (mh1,nh0): read A-mh1 (8); stage SB0(j+2); b0 from regs
#pragma unroll
    for (int mi = 0; mi < 4; ++mi) {
      af[mi][0] = *(const short8*)(bA + (wr * 128 + 64 + mi * 16 + lrow) * 64 + co0);
      af[mi][1] = *(const short8*)(bA + (wr * 128 + 64 + mi * 16 + lrow) * 64 + co1);
    }
    if (j + 2 < NT) STG_B0(cur, kt2);
    CFENCE;
    __builtin_amdgcn_s_barrier();
    __builtin_amdgcn_s_setprio(1);
    MFMA16(1, 0, b0);
    __builtin_amdgcn_s_setprio(0);
    __builtin_amdgcn_sched_barrier(0);
    __builtin_amdgcn_s_barrier();
    CFENCE;
    // ---- ph4 (mh1,nh1): no reads; stage SB1(j+2); gate before close barrier
    if (j + 2 < NT) STG_B1(cur, kt2);
    CFENCE;
    __builtin_amdgcn_s_barrier();
    __builtin_amdgcn_s_setprio(1);
    MFMA16(1, 1, b1);
    __builtin_amdgcn_s_setprio(0);
    if (j < NT - 2)       asm volatile("s_waitcnt vmcnt(6)" ::: "memory");
    else if (j == NT - 2) asm volatile("s_waitcnt vmcnt(0)" ::: "memory");
    __builtin_amdgcn_sched_barrier(0);
    __builtin_amdgcn_s_barrier();
    CFENCE;
  }

  // epilogue. frag (m,n): row_local = wr*128 + m*16 + (lane>>4)*4 + q,
  // col_local = (n>>1)*128 + wc*32 + (n&1)*16 + (lane&15)
  if (OUTF32) {
    const int rowb = m0 + wr * 128 + (lane >> 4) * 4;
#pragma unroll
    for (int n = 0; n < 4; ++n) {
      const int col = n0 + (n >> 1) * 128 + wc * 32 + (n & 1) * 16 + (lane & 15);
      const float bv = bias ? bias[col] : 0.f;
#pragma unroll
      for (int m = 0; m < 8; ++m)
#pragma unroll
        for (int q = 0; q < 4; ++q)
          ((float*)Cp)[(size_t)(rowb + m * 16 + q) * N + col] = acc[m][n][q] * scale + bv;
    }
  } else {
    // stage C tile in LDS (reuse staging buffers; all reads done at final barrier)
    u16* cls = lds;
    const int rowl = wr * 128 + (lane >> 4) * 4;
#pragma unroll
    for (int n = 0; n < 4; ++n) {
      const int coll = (n >> 1) * 128 + wc * 32 + (n & 1) * 16 + (lane & 15);
      const float bv = bias ? bias[n0 + coll] : 0.f;
#pragma unroll
      for (int m = 0; m < 8; ++m)
#pragma unroll
        for (int q = 0; q < 4; ++q)
          cls[(rowl + m * 16 + q) * 256 + coll] = f2bf(acc[m][n][q] * scale + bv);
    }
    __syncthreads();
    u16* Cu = (u16*)Cp;
#pragma unroll
    for (int ps = 0; ps < 16; ++ps) {
      const int f = ps * 512 + t;
      const int row = f >> 5, col8 = (f & 31) * 8;
      *(ushort8*)(Cu + (size_t)(m0 + row) * N + n0 + col8) =
          *(const ushort8*)(cls + row * 256 + col8);
    }
  }
#undef STG_A0
#undef STG_A1
#undef STG_B0
#undef STG_B1
#undef MFMA16
}

// ---------------- masked row softmax, bf16 in-place, z-folded ---------------
__global__ __launch_bounds__(256) void k_softmax(
    u16* __restrict__ s0, u16* __restrict__ s1,
    u16* __restrict__ s2, u16* __restrict__ s3, const int* __restrict__ ccnt)
{
  const int t = threadIdx.x, lane = t & 63, w = t >> 6;
  const int row = blockIdx.x, b = blockIdx.y;
  u16* sc = (b == 0) ? s0 : (b == 1) ? s1 : (b == 2) ? s2 : s3;
  const int Cb = ccnt[b];
  u16* p = sc + (size_t)row * SS + t * 16;
  ushort8 v0 = *(ushort8*)p, v1 = *(ushort8*)(p + 8);
  float x[16];
#pragma unroll
  for (int e = 0; e < 8; ++e) { x[e] = bf2f(v0[e]); x[8 + e] = bf2f(v1[e]); }
  const int cb0 = t * 16;
  float m = -1e30f;
#pragma unroll
  for (int e = 0; e < 16; ++e) if (cb0 + e < Cb) m = fmaxf(m, x[e]);
#pragma unroll
  for (int off = 32; off; off >>= 1) m = fmaxf(m, __shfl_xor(m, off));
  __shared__ float red[4], red2[4];
  if (lane == 0) red[w] = m;
  __syncthreads();
  m = fmaxf(fmaxf(red[0], red[1]), fmaxf(red[2], red[3]));
  float ssum = 0.f;
#pragma unroll
  for (int e = 0; e < 16; ++e) {
    float ev = (cb0 + e < Cb) ? __expf(x[e] - m) : 0.f;
    x[e] = ev; ssum += ev;
  }
#pragma unroll
  for (int off = 32; off; off >>= 1) ssum += __shfl_xor(ssum, off);
  if (lane == 0) red2[w] = ssum;
  __syncthreads();
  ssum = red2[0] + red2[1] + red2[2] + red2[3];
  const float inv = 1.f / ssum;
#pragma unroll
  for (int e = 0; e < 8; ++e) { v0[e] = f2bf(x[e] * inv); v1[e] = f2bf(x[8 + e] * inv); }
  *(ushort8*)p = v0; *(ushort8*)(p + 8) = v1;
}

// ---------------- bf16 transpose v[b][c][d] -> vT[b][d][c] ------------------
__global__ __launch_bounds__(256) void k_transpose(
    const u16* __restrict__ v, u16* __restrict__ vt)
{
  __shared__ u16 ts[64][80];
  const int t = threadIdx.x;
  const int d0 = blockIdx.x * 64, c0 = blockIdx.y * 64, b = blockIdx.z;
#pragma unroll
  for (int p = 0; p < 2; ++p) {
    const int idx = p * 256 + t, r = idx >> 3, cc = idx & 7;
    ushort8 val = *(const ushort8*)(v + ((size_t)b * SS + c0 + r) * DD + d0 + cc * 8);
    *(ushort8*)&ts[r][cc * 8] = val;
  }
  __syncthreads();
#pragma unroll
  for (int p = 0; p < 2; ++p) {
    const int idx = p * 256 + t, r = idx >> 3, cc = idx & 7;
    ushort8 o;
#pragma unroll
    for (int e = 0; e < 8; ++e) o[e] = ts[cc * 8 + e][r];
    *(ushort8*)(vt + ((size_t)b * DD + d0 + r) * SS + c0 + cc * 8) = o;
  }
}

// ---------------- loss finalize ---------------------------------------------
__global__ __launch_bounds__(256) void k_lossfin(
    const float* __restrict__ part, float* __restrict__ out)
{
  const int t = threadIdx.x, lane = t & 63, w = t >> 6;
  float s = 0.f;
  for (int i = t; i < 4096; i += 256) s += part[i];
#pragma unroll
  for (int off = 32; off; off >>= 1) s += __shfl_xor(s, off);
  __shared__ float r[4];
  if (lane == 0) r[w] = s;
  __syncthreads();
  if (t == 0) out[0] = (r[0] + r[1] + r[2] + r[3]) * (1.f / (NB * SS));
}

extern "C" void kernel_launch(void* const* d_in, const int* in_sizes, int n_in,
                              void* d_out, int out_size, void* d_ws, size_t ws_size,
                              hipStream_t stream) {
  const float* h  = (const float*)d_in[0];
  const int* plab = (const int*)d_in[1];
  const float* Wl = (const float*)d_in[2];
  const float* bl = (const float*)d_in[3];
  const float* Wq = (const float*)d_in[4];
  const float* bq = (const float*)d_in[5];
  const float* Wk = (const float*)d_in[6];
  const float* bk = (const float*)d_in[7];
  const float* Wv = (const float*)d_in[8];
  const float* bv = (const float*)d_in[9];
  const float* Wo = (const float*)d_in[10];
  const float* bo = (const float*)d_in[11];
  float* out = (float*)d_out;

  char* ws = (char*)d_ws;
  const size_t SZ = (size_t)NB * SS * DD * 2;  // 32 MB
  const size_t SD = (size_t)SS * DD;           // per-batch elems
  u16* h16      = (u16*)(ws + 0 * SZ);  // dead after q GEMM -> scores[2]
  u16* cemb     = (u16*)(ws + 1 * SZ);  // dead after k,v GEMM -> scores[3]
  u16* q        = (u16*)(ws + 2 * SZ);
  u16* kk       = (u16*)(ws + 3 * SZ);
  u16* vv       = (u16*)(ws + 4 * SZ);  // dead after transpose -> attended
  u16* vt       = (u16*)(ws + 5 * SZ);
  u16* Wt       = (u16*)(ws + 6 * SZ);  // 8 MB
  char* ws2     = ws + 6 * SZ + (size_t)4 * 1024 * 1024 * 2;
  int* pred     = (int*)ws2;
  int* cstart   = (int*)(ws2 + 65536);
  int* ccnt     = (int*)(ws2 + 65536 + 4 * (SS + 1) * 4);
  float* lossPart = (float*)(ws2 + 65536 + 4 * (SS + 1) * 4 + 64);
  u16* s0 = (u16*)d_out;                       // scores borrow d_out + dead bufs
  u16* s1 = (u16*)d_out + (size_t)SS * SS;
  u16* s2 = h16;
  u16* s3 = cemb;
  u16* att = vv;

  k_logits<<<dim3(NB * SS / 4), 256, 0, stream>>>(h, plab, Wl, bl, h16, pred, lossPart);
  k_wconv<<<dim3(4 * 1024 * 1024 / 256), 256, 0, stream>>>(Wq, Wk, Wv, Wo, Wt);
  k_scan<<<dim3(NB), 256, 0, stream>>>(pred, cstart, ccnt);
  k_pool<<<dim3(NB * SS / 4), 256, 0, stream>>>(h, cstart, ccnt, cemb);

  gemm256<0><<<dim3(DD / 256, NB * SS / 256, 1), 512, 0, stream>>>(
      h16, h16, h16, h16, Wt, 0, q, q, q, q, bq, 1.f, NB * SS, DD, DD);
  gemm256<0><<<dim3(DD / 256, NB * SS / 256, 1), 512, 0, stream>>>(
      cemb, cemb, cemb, cemb, Wt + (1 << 20), 0, kk, kk, kk, kk, bk, 1.f, NB * SS, DD, DD);
  gemm256<0><<<dim3(DD / 256, NB * SS / 256, 1), 512, 0, stream>>>(
      cemb, cemb, cemb, cemb, Wt + 2 * (1 << 20), 0, vv, vv, vv, vv, bv, 1.f, NB * SS, DD, DD);
  k_transpose<<<dim3(DD / 64, SS / 64, NB), 256, 0, stream>>>(vv, vt);

  const float scl = 1.f / 32.f;  // 1/sqrt(DC)
  gemm256<0><<<dim3(SS / 256, SS / 256, NB), 512, 0, stream>>>(
      q, q + SD, q + 2 * SD, q + 3 * SD, kk, (long)SD,
      s0, s1, s2, s3, nullptr, scl, SS, SS, DD);
  k_softmax<<<dim3(SS, NB), 256, 0, stream>>>(s0, s1, s2, s3, ccnt);
  gemm256<0><<<dim3(DD / 256, SS / 256, NB), 512, 0, stream>>>(
      s0, s1, s2, s3, vt, (long)SD,
      att, att + SD, att + 2 * SD, att + 3 * SD, nullptr, 1.f, SS, DD, SS);
  gemm256<1><<<dim3(DD / 256, NB * SS / 256, 1), 512, 0, stream>>>(
      att, att, att, att, Wt + 3 * (1 << 20), 0, out, out, out, out, bo, 1.f, NB * SS, DD, DD);
  k_lossfin<<<dim3(1), 256, 0, stream>>>(lossPart, out + (size_t)NB * SS * DD);
}